// Round 11
// baseline (2180.246 us; speedup 1.0000x reference)
//
#include <hip/hip_runtime.h>

// spectralAgg R11: DEFINITIVE PROBE ROUND (sacrificial timing).
// Four pure-read probes, each sized LONGER than the main kernel so all four
// appear in the top-5 rocprof rows with their own hbm_gbps:
//   p_seq      x6 : 3GB sequential           -> chip read ceiling
//   p_patch    x4 : 2GB exact R4 patch pattern -> the 2.6 TB/s hypothesis
//   p_row      x4 : 2GB 2KB-contiguous c-major -> row-band alternative
//   p_patch_nt x4 : 2GB patch pattern, nontemporal loads -> cache-bypass test
// Main kernel = R4 monolithic (proven, absmax 0.03125), runs last, fully
// overwrites d_out. reps passed as runtime args to block CSE/unroll tricks.

#define NW  512
#define HWs 262144
#define NS1 16
#define NS3 16

typedef __attribute__((ext_vector_type(4)))  __bf16 bf4;
typedef __attribute__((ext_vector_type(8)))  __bf16 bf8;
typedef __attribute__((ext_vector_type(16))) float  f32x16;
typedef __attribute__((ext_vector_type(4)))  float  f4v;

#define MFMA __builtin_amdgcn_mfma_f32_32x32x16_bf16
#define F4E(v,j) ((j)==0?(v).x:(j)==1?(v).y:(j)==2?(v).z:(v).w)

__device__ __forceinline__ void bar_lgkm() {
  asm volatile("s_waitcnt lgkmcnt(0)" ::: "memory");
  __builtin_amdgcn_s_barrier();
}

// ========================= probes =========================
extern "C" __global__ __launch_bounds__(256)
void p_seq(const f4v* __restrict__ x, float* __restrict__ dout, int nPass) {
  const int gid = blockIdx.x * 256 + threadIdx.x;
  const int stride = gridDim.x * 256;
  float acc = 0.f;
  for (int ps = 0; ps < nPass; ++ps)
    for (int i = gid; i < 33554432; i += stride) {      // full 512MB of x
      const f4v v = x[i];
      acc += v.x + v.y + v.z + v.w;
    }
  dout[gid] = acc;
}

extern "C" __global__ __launch_bounds__(256)
void p_patch(const float* __restrict__ x, float* __restrict__ dout, int reps) {
  const int wg = blockIdx.x;                  // 512 WGs = all patches (512MB/rep)
  const int b = wg >> 6, pp = wg & 63, pr = pp >> 3, pc = pp & 7;
  const float* xp = x + (size_t)b * 64 * HWs + (size_t)(pr * 64) * NW + pc * 64;
  const int t = threadIdx.x;
  const int c_ld = t >> 2, q_ld = t & 3;
  const float* g1 = xp + (size_t)c_ld * HWs + q_ld * 16;   // exact R4 loader
  float acc = 0.f;
  for (int rep = 0; rep < reps; ++rep)
    for (int st = 0; st < 16; ++st) {
      const float* gp = g1 + (size_t)st * 4 * NW;
#pragma unroll
      for (int rl = 0; rl < 4; ++rl)
#pragma unroll
        for (int j = 0; j < 4; ++j) {
          const f4v v = *(const f4v*)(gp + (size_t)rl * NW + j * 4);
          acc += v.x + v.y + v.z + v.w;
        }
    }
  dout[wg * 256 + t] = acc;
}

extern "C" __global__ __launch_bounds__(256)
void p_patch_nt(const float* __restrict__ x, float* __restrict__ dout, int reps) {
  const int wg = blockIdx.x;
  const int b = wg >> 6, pp = wg & 63, pr = pp >> 3, pc = pp & 7;
  const float* xp = x + (size_t)b * 64 * HWs + (size_t)(pr * 64) * NW + pc * 64;
  const int t = threadIdx.x;
  const int c_ld = t >> 2, q_ld = t & 3;
  const float* g1 = xp + (size_t)c_ld * HWs + q_ld * 16;
  float acc = 0.f;
  for (int rep = 0; rep < reps; ++rep)
    for (int st = 0; st < 16; ++st) {
      const float* gp = g1 + (size_t)st * 4 * NW;
#pragma unroll
      for (int rl = 0; rl < 4; ++rl)
#pragma unroll
        for (int j = 0; j < 4; ++j) {
          const f4v v = __builtin_nontemporal_load((const f4v*)(gp + (size_t)rl * NW + j * 4));
          acc += v.x + v.y + v.z + v.w;
        }
    }
  dout[wg * 256 + t] = acc;
}

extern "C" __global__ __launch_bounds__(256)
void p_row(const float* __restrict__ x, float* __restrict__ dout, int reps) {
  const int wg = blockIdx.x;                  // 512 = img*64 + band (512MB/rep)
  const int img = wg >> 6, band = wg & 63;
  const int t = threadIdx.x;
  const int half = t >> 7, col = t & 127;
  const float* xb = x + (size_t)img * 64 * HWs + (size_t)(band * 8) * NW + col * 4;
  float acc = 0.f;
  for (int rep = 0; rep < reps; ++rep)
    for (int rp = 0; rp < 4; ++rp)
#pragma unroll 8
      for (int c = 0; c < 64; ++c) {          // c-major, 2KB contiguous per (c,row)
        const f4v v = *(const f4v*)(xb + (size_t)c * HWs + (size_t)(rp * 2 + half) * NW);
        acc += v.x + v.y + v.z + v.w;
      }
  dout[wg * 256 + t] = acc;
}

// ========================= main: R4 monolithic (proven) =========================
__device__ __forceinline__ void fb_load1(const float* g1, int st, float4 (&R)[16]) {
  const float* gp = g1 + (size_t)st * 4 * NW;
#pragma unroll
  for (int rl = 0; rl < 4; ++rl)
#pragma unroll
    for (int j = 0; j < 4; ++j)
      R[rl * 4 + j] = *(const float4*)(gp + (size_t)rl * NW + j * 4);
}
__device__ __forceinline__ void fb_cvtw1(char* wH, char* wL, int q_ld, int swzw,
                                         const float4 (&R)[16]) {
#pragma unroll
  for (int rl = 0; rl < 4; ++rl)
#pragma unroll
    for (int s = 0; s < 2; ++s) {
      const float4 va = R[rl * 4 + s * 2], vb = R[rl * 4 + s * 2 + 1];
      const float f[8] = {va.x, va.y, va.z, va.w, vb.x, vb.y, vb.z, vb.w};
      bf8 h, lo;
#pragma unroll
      for (int e = 0; e < 8; ++e) { h[e] = (__bf16)f[e]; lo[e] = (__bf16)(f[e] - (float)h[e]); }
      const int boff = (rl * 128 + q_ld * 32 + s * 16) ^ swzw;
      *(bf8*)(wH + boff) = h;
      *(bf8*)(wL + boff) = lo;
    }
}
__device__ __forceinline__ void fb_load3(const float* g3, int st, float4 (&R)[16]) {
  const float* gp = g3 + (size_t)st * 4 * NW;
#pragma unroll
  for (int cc = 0; cc < 4; ++cc)
#pragma unroll
    for (int j = 0; j < 4; ++j)
      R[cc * 4 + j] = *(const float4*)(gp + (size_t)cc * HWs + j * 4);
}
__device__ __forceinline__ void fb_cvtw3(char* sT, int cg, int iq, const float4 (&R)[16]) {
#pragma unroll
  for (int w = 0; w < 16; ++w) {
    bf4 q;
#pragma unroll
    for (int cc = 0; cc < 4; ++cc) q[cc] = (__bf16)F4E(R[cc * 4 + (w >> 2)], w & 3);
    const int iloc = iq * 16 + w;
    const int sw = ((iloc & 15) ^ ((iloc >> 4) & 7)) << 4;
    const int boff = (iloc & 127) * 256 + ((((iloc >> 7) << 7) + cg * 8) ^ sw);
    *(bf4*)(sT + boff) = q;
  }
}
extern "C" __global__ __launch_bounds__(256, 2)
void spectralAgg_main(const float* __restrict__ x, const float* __restrict__ g,
                      float* __restrict__ out) {
  __shared__ char lds[73728];
  char* sH = lds;
  char* sL = lds + 32768;
  char* sA = lds + 65536;
  const int t = threadIdx.x, wv = t >> 6, l = t & 63, l31 = l & 31, hh = l >> 5;
  const int wg = blockIdx.x, b = wg >> 6, pp = wg & 63, pr = pp >> 3, pcq = pp & 7;
  const size_t pbase = (size_t)b*64*HWs + (size_t)(pr*64)*NW + (size_t)(pcq*64);
  const float* xp = x + pbase;
  float* op = out + pbase;
  const int c_ld = t >> 2, q_ld = t & 3;
  const float* g1 = xp + (size_t)c_ld * HWs + q_ld * 16;
  char* wH = sH + c_ld * 512;
  char* wL = sL + c_ld * 512;
  const int swzw = (c_ld & 31) << 4;
  const int ct = wv >> 1, dt = wv & 1;
  const char* pA  = sH + (size_t)(ct*32+l31)*512;
  const char* pBh = sH + (size_t)(dt*32+l31)*512;
  const char* pBl = sL + (size_t)(dt*32+l31)*512;
  const int swzr = l31 << 4;
  f32x16 accG, accS;
#pragma unroll
  for (int i = 0; i < 16; ++i) { accG[i] = 0.f; accS[i] = 0.f; }
  float4 ra[16], rb[16];
  fb_load1(g1, 0, ra);
  for (int st = 0; st < NS1; ++st) {
    fb_load1(g1, (st + 1 < NS1) ? st + 1 : st, rb);
    fb_cvtw1(wH, wL, q_ld, swzw, ra);
    bar_lgkm();
#pragma unroll
    for (int k0 = 0; k0 < 16; ++k0) {
      const int off = (k0 * 32 + hh * 16) ^ swzr;
      const bf8 a  = *(const bf8*)(pA + off);
      const bf8 bh = *(const bf8*)(pBh + off);
      const bf8 bl = *(const bf8*)(pBl + off);
      accG = MFMA(a, bh, accG, 0, 0, 0);
      accS = MFMA(a, bl, accS, 0, 0, 0);
    }
    bar_lgkm();
#pragma unroll
    for (int e = 0; e < 16; ++e) ra[e] = rb[e];
  }
  float* S_lds = (float*)sL;
  float* E_lds = (float*)sH;
#pragma unroll
  for (int i = 0; i < 16; ++i) {
    const int cr = ct*32 + (i&3) + ((i>>2)<<3) + (hh<<2);
    S_lds[cr*64 + dt*32 + l31] = accS[i];
  }
  bar_lgkm();
#pragma unroll
  for (int i = 0; i < 16; ++i) {
    const int cr = ct*32 + (i&3) + ((i>>2)<<3) + (hh<<2);
    const int d = dt*32 + l31;
    E_lds[cr*64 + d] = accG[i] + accS[i] + S_lds[d*64 + cr];
  }
  bar_lgkm();
  const int cg = t >> 4, iq = t & 15;
  const float* g3 = xp + (size_t)(cg*4)*HWs + (size_t)(iq>>2)*NW + (iq&3)*16;
  fb_load3(g3, 0, ra);
  const float gs = 1.0f + g[0];
#pragma unroll 1
  for (int rr = 0; rr < 16; ++rr) {
    const int c = wv*16 + rr;
    const float e = E_lds[c*64 + l];
    float mn = e;
#pragma unroll
    for (int o = 32; o; o >>= 1) mn = fminf(mn, __shfl_xor(mn, o));
    const float w = __expf(mn - e);
    float s = w;
#pragma unroll
    for (int o = 32; o; o >>= 1) s += __shfl_xor(s, o);
    *(__bf16*)(sA + c*128 + ((l*2) ^ ((c&7)<<4))) = (__bf16)(gs * w / s);
  }
  bar_lgkm();
  bf8 bfr[2][4];
#pragma unroll
  for (int c2 = 0; c2 < 2; ++c2)
#pragma unroll
    for (int k0 = 0; k0 < 4; ++k0)
      bfr[c2][k0] = *(const bf8*)(sA + (size_t)(c2*32+l31)*128 +
                                  ((k0*32 + hh*16) ^ ((l31&7)<<4)));
  for (int st = 0; st < NS3; ++st) {
    fb_load3(g3, (st + 1 < NS3) ? st + 1 : st, rb);
    fb_cvtw3(sH, cg, iq, ra);
    bar_lgkm();
    f32x16 oo0[2], oo1[2];
#pragma unroll
    for (int it = 0; it < 2; ++it)
#pragma unroll
      for (int i = 0; i < 16; ++i) { oo0[it][i] = 0.f; oo1[it][i] = 0.f; }
#pragma unroll
    for (int it = 0; it < 2; ++it) {
      const int i = wv*64 + it*32 + l31;
      const char* base = sH + (size_t)(i & 127) * 256;
      const int hb = (i >> 7) * 128;
      const int sw = ((i & 15) ^ ((i >> 4) & 7)) << 4;
#pragma unroll
      for (int k0 = 0; k0 < 4; ++k0) {
        const bf8 pa = *(const bf8*)(base + ((hb + k0*32 + hh*16) ^ sw));
        oo0[it] = MFMA(pa, bfr[0][k0], oo0[it], 0, 0, 0);
        oo1[it] = MFMA(pa, bfr[1][k0], oo1[it], 0, 0, 0);
      }
    }
#pragma unroll
    for (int it = 0; it < 2; ++it)
#pragma unroll
      for (int rq = 0; rq < 4; ++rq) {
        const int iloc = wv*64 + it*32 + rq*8 + hh*4;
        const int gi = st*256 + iloc;
        float* oprow = op + (size_t)(gi >> 6)*NW + (gi & 63);
        float4 q0; q0.x=oo0[it][rq*4+0]; q0.y=oo0[it][rq*4+1]; q0.z=oo0[it][rq*4+2]; q0.w=oo0[it][rq*4+3];
        *(float4*)(oprow + (size_t)l31*HWs) = q0;
        float4 q1; q1.x=oo1[it][rq*4+0]; q1.y=oo1[it][rq*4+1]; q1.z=oo1[it][rq*4+2]; q1.w=oo1[it][rq*4+3];
        *(float4*)(oprow + (size_t)(32+l31)*HWs) = q1;
      }
    bar_lgkm();
#pragma unroll
    for (int e = 0; e < 16; ++e) ra[e] = rb[e];
  }
}

extern "C" void kernel_launch(void* const* d_in, const int* in_sizes, int n_in,
                              void* d_out, int out_size, void* d_ws, size_t ws_size,
                              hipStream_t stream) {
  const float* x = (const float*)d_in[0];
  const float* g = (const float*)d_in[1];
  float* o = (float*)d_out;
  // probes sized LONGER than main so all 4 land in top-5 rocprof rows
  p_seq     <<<dim3(2048), dim3(256), 0, stream>>>((const f4v*)x, o, 6);
  p_patch   <<<dim3(512),  dim3(256), 0, stream>>>(x, o, 4);
  p_row     <<<dim3(512),  dim3(256), 0, stream>>>(x, o, 4);
  p_patch_nt<<<dim3(512),  dim3(256), 0, stream>>>(x, o, 4);
  // real kernel (R4, proven) -- fully overwrites d_out
  spectralAgg_main<<<dim3(512), dim3(256), 0, stream>>>(x, g, o);
}

// Round 12
// 402.581 us; speedup vs baseline: 5.4157x; 5.4157x over previous
//
#include <hip/hip_runtime.h>

// spectralAgg R12: row-band 3-kernel pipeline (lean).
//  K1: read x in 1KB runs, partial Gram per (b,pr,hq,wh) -> Epart[pat][hq] (32MB).
//      (R9 k1 minus the 256MB pack -- proven correct in R9.)
//  K2: reduce 4 partials + softmax(-E) (min-stab, gamma folded) -> A bf16 (4MB).
//  K3: row-band PV: re-read x in 1KB runs in REVERSE band order (L3 reuse of
//      K1 tail), in-register transpose -> [256w][144B] LDS tile (b128 writes),
//      MFMA with A-frags from global, 128B-per-channel line stores.
// Fallback: proven R4 monolithic if ws_size < 36MB.

#define NW  512
#define HWs 262144

typedef __attribute__((ext_vector_type(4)))  __bf16 bf4;
typedef __attribute__((ext_vector_type(8)))  __bf16 bf8;
typedef __attribute__((ext_vector_type(16))) float  f32x16;

#define MFMA __builtin_amdgcn_mfma_f32_32x32x16_bf16
#define F4E(v,j) ((j)==0?(v).x:(j)==1?(v).y:(j)==2?(v).z:(v).w)

__device__ __forceinline__ void bar_lgkm() {
  asm volatile("s_waitcnt lgkmcnt(0)" ::: "memory");
  __builtin_amdgcn_s_barrier();
}

__device__ __forceinline__ int soff(int c, int rb) {
  return c * 512 + (rb ^ ((c & 31) << 4));
}

// ======================= K1: partial Gram (row-band) =======================
extern "C" __global__ __launch_bounds__(512)
void k1_gram(const float* __restrict__ x, float* __restrict__ ep) {
  __shared__ char lds[66560];        // sHi 32KB + sLo 32KB; overlay S_lds
  char* sHi = lds;                   // [64 c][512 B], XOR-swizzled by c
  char* sLo = lds + 32768;
  float* S_lds = (float*)lds;        // [4 p][64*65] f32 (after K loop)

  const int T   = threadIdx.x;
  const int wv8 = T >> 6;
  const int l   = T & 63;
  const int l31 = l & 31, hh = l >> 5;

  const int bid = blockIdx.x;        // b*64 + pr*8 + hq*2 + wh
  const int wh = bid & 1;
  const int hq = (bid >> 1) & 3;
  const int pr = (bid >> 3) & 7;
  const int b  = bid >> 6;

  const int pl = wv8 & 3;            // wave's patch within the half
  const int ct = wv8 >> 2;           // wave's E row-half
  const int pat  = b * 64 + pr * 8 + wh * 4 + pl;
  const int row0 = pr * 64 + hq * 16;

  const float* xb = x + (size_t)b * 64 * HWs + (size_t)row0 * NW + wh * 256 + l * 4;

  f32x16 G0, G1, S0, S1;
#pragma unroll
  for (int i = 0; i < 16; ++i) { G0[i]=0.f; G1[i]=0.f; S0[i]=0.f; S1[i]=0.f; }

  float4 rA[8], rB[8];
#pragma unroll
  for (int j = 0; j < 8; ++j)
    rA[j] = *(const float4*)(xb + (size_t)(wv8 * 8 + j) * HWs);

  for (int r = 0; r < 16; ++r) {
    if (r + 1 < 16) {
#pragma unroll
      for (int j = 0; j < 8; ++j)
        rB[j] = *(const float4*)(xb + (size_t)(wv8 * 8 + j) * HWs + (size_t)(r + 1) * NW);
    }
#pragma unroll
    for (int j = 0; j < 8; ++j) {
      const int c = wv8 * 8 + j;
      const float4 v = rA[j];
      bf4 h, lo;
      h[0]=(__bf16)v.x; h[1]=(__bf16)v.y; h[2]=(__bf16)v.z; h[3]=(__bf16)v.w;
      lo[0]=(__bf16)(v.x-(float)h[0]); lo[1]=(__bf16)(v.y-(float)h[1]);
      lo[2]=(__bf16)(v.z-(float)h[2]); lo[3]=(__bf16)(v.w-(float)h[3]);
      const int off = c * 512 + ((l * 8) ^ ((c & 31) << 4));
      *(bf4*)(sHi + off) = h;
      *(bf4*)(sLo + off) = lo;
    }
    bar_lgkm();
#pragma unroll
    for (int ks = 0; ks < 4; ++ks) {
      const int rb = pl * 128 + ks * 32 + hh * 16;
      const int ca = ct * 32 + l31;
      const bf8 a   = *(const bf8*)(sHi + soff(ca, rb));
      const bf8 bh0 = *(const bf8*)(sHi + soff(l31, rb));
      const bf8 bh1 = *(const bf8*)(sHi + soff(32 + l31, rb));
      const bf8 bl0 = *(const bf8*)(sLo + soff(l31, rb));
      const bf8 bl1 = *(const bf8*)(sLo + soff(32 + l31, rb));
      G0 = MFMA(a, bh0, G0, 0, 0, 0);
      G1 = MFMA(a, bh1, G1, 0, 0, 0);
      S0 = MFMA(a, bl0, S0, 0, 0, 0);
      S1 = MFMA(a, bl1, S1, 0, 0, 0);
    }
    bar_lgkm();
#pragma unroll
    for (int e = 0; e < 8; ++e) rA[e] = rB[e];
  }

  // epilogue: S -> LDS, then Epart = G + S + S^T
#pragma unroll
  for (int i = 0; i < 16; ++i) {
    const int cr = ct * 32 + (i & 3) + ((i >> 2) << 3) + (hh << 2);
    S_lds[pl * 4160 + cr * 65 + l31]      = S0[i];
    S_lds[pl * 4160 + cr * 65 + 32 + l31] = S1[i];
  }
  bar_lgkm();
  float* epb = ep + ((size_t)(pat * 4 + hq) << 12);
#pragma unroll
  for (int i = 0; i < 16; ++i) {
    const int cr = ct * 32 + (i & 3) + ((i >> 2) << 3) + (hh << 2);
    epb[cr * 64 + l31]      = G0[i] + S0[i] + S_lds[pl * 4160 + l31 * 65 + cr];
    epb[cr * 64 + 32 + l31] = G1[i] + S1[i] + S_lds[pl * 4160 + (32 + l31) * 65 + cr];
  }
}

// ======================= K2: reduce + softmax =======================
extern "C" __global__ __launch_bounds__(256)
void k2_softmax(const float* __restrict__ ep, const float* __restrict__ g,
                __bf16* __restrict__ attn) {
  const int pat = blockIdx.x;
  const int w4 = threadIdx.x >> 6, l = threadIdx.x & 63;
  const float gs = 1.0f + g[0];
  const float* e0 = ep + ((size_t)(pat * 4) << 12);
#pragma unroll 1
  for (int cc = 0; cc < 16; ++cc) {
    const int c = w4 * 16 + cc;
    const int o = c * 64 + l;
    const float e = e0[o] + e0[4096 + o] + e0[8192 + o] + e0[12288 + o];
    float mn = e;
#pragma unroll
    for (int off = 32; off; off >>= 1) mn = fminf(mn, __shfl_xor(mn, off));
    const float w = __expf(mn - e);
    float s = w;
#pragma unroll
    for (int off = 32; off; off >>= 1) s += __shfl_xor(s, off);
    attn[(size_t)pat * 4096 + o] = (__bf16)(gs * w / s);
  }
}

// ======================= K3: row-band PV =======================
extern "C" __global__ __launch_bounds__(512, 4)
void k3_pv(const float* __restrict__ x, const __bf16* __restrict__ attn,
           float* __restrict__ out) {
  __shared__ char pT[256 * 144];     // [256 w][144B]: w rows, 64 d bf16 + pad

  const int T   = threadIdx.x;
  const int wv8 = T >> 6;
  const int l   = T & 63;
  const int l31 = l & 31, hh = l >> 5;

  const int bid = 511 - (int)blockIdx.x;   // reverse order: L3 reuse of K1 tail
  const int wh = bid & 1;
  const int hq = (bid >> 1) & 3;
  const int pr = (bid >> 3) & 7;
  const int b  = bid >> 6;
  const int row0 = pr * 64 + hq * 16;

  const float* xb = x + (size_t)b * 64 * HWs + (size_t)row0 * NW + wh * 256 + l * 4;
  float* ob = out + (size_t)b * 64 * HWs + (size_t)row0 * NW + wh * 256;

  const int pl = wv8 & 3, ih = wv8 >> 2;   // wave: patch pl, w-block ih
  const int pat = b * 64 + pr * 8 + wh * 4 + pl;

  // A-frags (stage-invariant) from global (layout proven in R9 k3)
  bf8 af[2][4];
#pragma unroll
  for (int mt = 0; mt < 2; ++mt)
#pragma unroll
    for (int ks = 0; ks < 4; ++ks)
      af[mt][ks] = *(const bf8*)(attn + (size_t)pat * 4096 +
                                 (mt * 32 + l31) * 64 + ks * 16 + hh * 8);

  float4 rA[8], rB[8];
#pragma unroll
  for (int j = 0; j < 8; ++j)
    rA[j] = *(const float4*)(xb + (size_t)(wv8 * 8 + j) * HWs);

  for (int r = 0; r < 16; ++r) {
    if (r + 1 < 16) {
#pragma unroll
      for (int j = 0; j < 8; ++j)
        rB[j] = *(const float4*)(xb + (size_t)(wv8 * 8 + j) * HWs + (size_t)(r + 1) * NW);
    }
    // in-register transpose: thread holds 8 consecutive c x 4 w -> 4 b128 writes
#pragma unroll
    for (int q = 0; q < 4; ++q) {
      bf8 v;
#pragma unroll
      for (int j = 0; j < 8; ++j) v[j] = (__bf16)F4E(rA[j], q);
      *(bf8*)(pT + (size_t)(l * 4 + q) * 144 + wv8 * 16) = v;
    }
    bar_lgkm();

    f32x16 o0, o1;
#pragma unroll
    for (int i = 0; i < 16; ++i) { o0[i] = 0.f; o1[i] = 0.f; }
    const int wrow = pl * 64 + ih * 32 + l31;
#pragma unroll
    for (int ks = 0; ks < 4; ++ks) {
      const bf8 pa = *(const bf8*)(pT + (size_t)wrow * 144 + ks * 32 + hh * 16);
      o0 = MFMA(pa, af[0][ks], o0, 0, 0, 0);
      o1 = MFMA(pa, af[1][ks], o1, 0, 0, 0);
    }
#pragma unroll
    for (int rq = 0; rq < 4; ++rq) {
      const int w = pl * 64 + ih * 32 + rq * 8 + hh * 4;
      float* orow = ob + (size_t)r * NW + w;
      float4 q0; q0.x=o0[rq*4+0]; q0.y=o0[rq*4+1]; q0.z=o0[rq*4+2]; q0.w=o0[rq*4+3];
      *(float4*)(orow + (size_t)l31 * HWs) = q0;
      float4 q1; q1.x=o1[rq*4+0]; q1.y=o1[rq*4+1]; q1.z=o1[rq*4+2]; q1.w=o1[rq*4+3];
      *(float4*)(orow + (size_t)(32 + l31) * HWs) = q1;
    }
    bar_lgkm();
#pragma unroll
    for (int e = 0; e < 8; ++e) rA[e] = rB[e];
  }
}

// ======================= fallback: R4 monolithic (proven) =======================
#define NS1 16
#define NS3 16
__device__ __forceinline__ void fb_load1(const float* g1, int st, float4 (&R)[16]) {
  const float* gp = g1 + (size_t)st * 4 * NW;
#pragma unroll
  for (int rl = 0; rl < 4; ++rl)
#pragma unroll
    for (int j = 0; j < 4; ++j)
      R[rl * 4 + j] = *(const float4*)(gp + (size_t)rl * NW + j * 4);
}
__device__ __forceinline__ void fb_cvtw1(char* wH, char* wL, int q_ld, int swzw,
                                         const float4 (&R)[16]) {
#pragma unroll
  for (int rl = 0; rl < 4; ++rl)
#pragma unroll
    for (int s = 0; s < 2; ++s) {
      const float4 va = R[rl * 4 + s * 2], vb = R[rl * 4 + s * 2 + 1];
      const float f[8] = {va.x, va.y, va.z, va.w, vb.x, vb.y, vb.z, vb.w};
      bf8 h, lo;
#pragma unroll
      for (int e = 0; e < 8; ++e) { h[e] = (__bf16)f[e]; lo[e] = (__bf16)(f[e] - (float)h[e]); }
      const int boff = (rl * 128 + q_ld * 32 + s * 16) ^ swzw;
      *(bf8*)(wH + boff) = h;
      *(bf8*)(wL + boff) = lo;
    }
}
__device__ __forceinline__ void fb_load3(const float* g3, int st, float4 (&R)[16]) {
  const float* gp = g3 + (size_t)st * 4 * NW;
#pragma unroll
  for (int cc = 0; cc < 4; ++cc)
#pragma unroll
    for (int j = 0; j < 4; ++j)
      R[cc * 4 + j] = *(const float4*)(gp + (size_t)cc * HWs + j * 4);
}
__device__ __forceinline__ void fb_cvtw3(char* sT, int cg, int iq, const float4 (&R)[16]) {
#pragma unroll
  for (int w = 0; w < 16; ++w) {
    bf4 q;
#pragma unroll
    for (int cc = 0; cc < 4; ++cc) q[cc] = (__bf16)F4E(R[cc * 4 + (w >> 2)], w & 3);
    const int iloc = iq * 16 + w;
    const int sw = ((iloc & 15) ^ ((iloc >> 4) & 7)) << 4;
    const int boff = (iloc & 127) * 256 + ((((iloc >> 7) << 7) + cg * 8) ^ sw);
    *(bf4*)(sT + boff) = q;
  }
}
extern "C" __global__ __launch_bounds__(256, 2)
void spectralAgg_fallback(const float* __restrict__ x, const float* __restrict__ g,
                          float* __restrict__ out) {
  __shared__ char lds[73728];
  char* sH = lds;
  char* sL = lds + 32768;
  char* sA = lds + 65536;
  const int t = threadIdx.x, wv = t >> 6, l = t & 63, l31 = l & 31, hh = l >> 5;
  const int wg = blockIdx.x, b = wg >> 6, pp = wg & 63, pr = pp >> 3, pcq = pp & 7;
  const size_t pbase = (size_t)b*64*HWs + (size_t)(pr*64)*NW + (size_t)(pcq*64);
  const float* xp = x + pbase;
  float* op = out + pbase;
  const int c_ld = t >> 2, q_ld = t & 3;
  const float* g1 = xp + (size_t)c_ld * HWs + q_ld * 16;
  char* wH = sH + c_ld * 512;
  char* wL = sL + c_ld * 512;
  const int swzw = (c_ld & 31) << 4;
  const int ct = wv >> 1, dt = wv & 1;
  const char* pA  = sH + (size_t)(ct*32+l31)*512;
  const char* pBh = sH + (size_t)(dt*32+l31)*512;
  const char* pBl = sL + (size_t)(dt*32+l31)*512;
  const int swzr = l31 << 4;
  f32x16 accG, accS;
#pragma unroll
  for (int i = 0; i < 16; ++i) { accG[i] = 0.f; accS[i] = 0.f; }
  float4 ra[16], rb[16];
  fb_load1(g1, 0, ra);
  for (int st = 0; st < NS1; ++st) {
    fb_load1(g1, (st + 1 < NS1) ? st + 1 : st, rb);
    fb_cvtw1(wH, wL, q_ld, swzw, ra);
    bar_lgkm();
#pragma unroll
    for (int k0 = 0; k0 < 16; ++k0) {
      const int off = (k0 * 32 + hh * 16) ^ swzr;
      const bf8 a  = *(const bf8*)(pA + off);
      const bf8 bh = *(const bf8*)(pBh + off);
      const bf8 bl = *(const bf8*)(pBl + off);
      accG = MFMA(a, bh, accG, 0, 0, 0);
      accS = MFMA(a, bl, accS, 0, 0, 0);
    }
    bar_lgkm();
#pragma unroll
    for (int e = 0; e < 16; ++e) ra[e] = rb[e];
  }
  float* S_lds = (float*)sL;
  float* E_lds = (float*)sH;
#pragma unroll
  for (int i = 0; i < 16; ++i) {
    const int cr = ct*32 + (i&3) + ((i>>2)<<3) + (hh<<2);
    S_lds[cr*64 + dt*32 + l31] = accS[i];
  }
  bar_lgkm();
#pragma unroll
  for (int i = 0; i < 16; ++i) {
    const int cr = ct*32 + (i&3) + ((i>>2)<<3) + (hh<<2);
    const int d = dt*32 + l31;
    E_lds[cr*64 + d] = accG[i] + accS[i] + S_lds[d*64 + cr];
  }
  bar_lgkm();
  const int cg = t >> 4, iq = t & 15;
  const float* g3 = xp + (size_t)(cg*4)*HWs + (size_t)(iq>>2)*NW + (iq&3)*16;
  fb_load3(g3, 0, ra);
  const float gs = 1.0f + g[0];
#pragma unroll 1
  for (int rr = 0; rr < 16; ++rr) {
    const int c = wv*16 + rr;
    const float e = E_lds[c*64 + l];
    float mn = e;
#pragma unroll
    for (int o = 32; o; o >>= 1) mn = fminf(mn, __shfl_xor(mn, o));
    const float w = __expf(mn - e);
    float s = w;
#pragma unroll
    for (int o = 32; o; o >>= 1) s += __shfl_xor(s, o);
    *(__bf16*)(sA + c*128 + ((l*2) ^ ((c&7)<<4))) = (__bf16)(gs * w / s);
  }
  bar_lgkm();
  bf8 bfr[2][4];
#pragma unroll
  for (int c2 = 0; c2 < 2; ++c2)
#pragma unroll
    for (int k0 = 0; k0 < 4; ++k0)
      bfr[c2][k0] = *(const bf8*)(sA + (size_t)(c2*32+l31)*128 +
                                  ((k0*32 + hh*16) ^ ((l31&7)<<4)));
  for (int st = 0; st < NS3; ++st) {
    fb_load3(g3, (st + 1 < NS3) ? st + 1 : st, rb);
    fb_cvtw3(sH, cg, iq, ra);
    bar_lgkm();
    f32x16 oo0[2], oo1[2];
#pragma unroll
    for (int it = 0; it < 2; ++it)
#pragma unroll
      for (int i = 0; i < 16; ++i) { oo0[it][i] = 0.f; oo1[it][i] = 0.f; }
#pragma unroll
    for (int it = 0; it < 2; ++it) {
      const int i = wv*64 + it*32 + l31;
      const char* base = sH + (size_t)(i & 127) * 256;
      const int hb = (i >> 7) * 128;
      const int sw = ((i & 15) ^ ((i >> 4) & 7)) << 4;
#pragma unroll
      for (int k0 = 0; k0 < 4; ++k0) {
        const bf8 pa = *(const bf8*)(base + ((hb + k0*32 + hh*16) ^ sw));
        oo0[it] = MFMA(pa, bfr[0][k0], oo0[it], 0, 0, 0);
        oo1[it] = MFMA(pa, bfr[1][k0], oo1[it], 0, 0, 0);
      }
    }
#pragma unroll
    for (int it = 0; it < 2; ++it)
#pragma unroll
      for (int rq = 0; rq < 4; ++rq) {
        const int iloc = wv*64 + it*32 + rq*8 + hh*4;
        const int gi = st*256 + iloc;
        float* oprow = op + (size_t)(gi >> 6)*NW + (gi & 63);
        float4 q0; q0.x=oo0[it][rq*4+0]; q0.y=oo0[it][rq*4+1]; q0.z=oo0[it][rq*4+2]; q0.w=oo0[it][rq*4+3];
        *(float4*)(oprow + (size_t)l31*HWs) = q0;
        float4 q1; q1.x=oo1[it][rq*4+0]; q1.y=oo1[it][rq*4+1]; q1.z=oo1[it][rq*4+2]; q1.w=oo1[it][rq*4+3];
        *(float4*)(oprow + (size_t)(32+l31)*HWs) = q1;
      }
    bar_lgkm();
#pragma unroll
    for (int e = 0; e < 16; ++e) ra[e] = rb[e];
  }
}

extern "C" void kernel_launch(void* const* d_in, const int* in_sizes, int n_in,
                              void* d_out, int out_size, void* d_ws, size_t ws_size,
                              hipStream_t stream) {
  const float* x = (const float*)d_in[0];
  const float* g = (const float*)d_in[1];
  float* o = (float*)d_out;
  const size_t epB = (size_t)512 * 4 * 4096 * 4;   // 32 MB
  const size_t aB  = (size_t)512 * 4096 * 2;       // 4 MB
  if (ws_size >= epB + aB) {
    float*  ep   = (float*)d_ws;
    __bf16* attn = (__bf16*)((char*)d_ws + epB);
    k1_gram   <<<dim3(512), dim3(512), 0, stream>>>(x, ep);
    k2_softmax<<<dim3(512), dim3(256), 0, stream>>>(ep, g, attn);
    k3_pv     <<<dim3(512), dim3(512), 0, stream>>>(x, attn, o);
  } else {
    spectralAgg_fallback<<<dim3(512), dim3(256), 0, stream>>>(x, g, o);
  }
}